// Round 20
// baseline (120.869 us; speedup 1.0000x reference)
//
#include <hip/hip_runtime.h>
#include <cmath>

typedef __bf16 bf16;
typedef __bf16 bf16x8 __attribute__((ext_vector_type(8)));
typedef float f32x4 __attribute__((ext_vector_type(4)));

#define SBAR() __builtin_amdgcn_sched_barrier(0)

// B=16, C_IN=256, H=W=64, C_OUT=256, 3x3, stride 1, pad 1, CURV=1

__device__ inline void gload16(const void* g, void* l) {
    __builtin_amdgcn_global_load_lds(
        (const __attribute__((address_space(1))) unsigned int*)g,
        (__attribute__((address_space(3))) unsigned int*)l, 16, 0, 0);
}

// ---------------------------------------------------------------------------
// Fused weight prep: blocks 0..71 build zt5[s][gran4][co256][8ch] bf16;
// blocks 72..327 compute column constants zn/ch/sh (one co per block).
__global__ void k_prep(const float* __restrict__ z, const float* __restrict__ r,
                       bf16* __restrict__ zt5, float* __restrict__ zn,
                       float* __restrict__ ch, float* __restrict__ sh) {
    int blk = blockIdx.x;
    if (blk < 72) {
        int cc = blk / 9, tap = blk % 9;
        int co = threadIdx.x;
#pragma unroll
        for (int g = 0; g < 4; ++g) {
            bf16x8 pk;
#pragma unroll
            for (int e = 0; e < 8; ++e) {
                int c = cc * 32 + g * 8 + e;
                pk[e] = (bf16)z[(size_t)(c * 9 + tap) * 256 + co];
            }
            *(bf16x8*)(zt5 + ((size_t)(blk * 4 + g) * 256 + co) * 8) = pk;
        }
    } else {
        __shared__ float red[256];
        int co = blk - 72, t = threadIdx.x;
        float s = 0.f;
        for (int i = 0; i < 9; ++i) {
            float v = z[(size_t)(i * 256 + t) * 256 + co];
            s += v * v;
        }
        red[t] = s;
        __syncthreads();
        for (int off = 128; off >= 1; off >>= 1) {
            if (t < off) red[t] += red[t + off];
            __syncthreads();
        }
        if (t == 0) {
            zn[co] = fmaxf(sqrtf(red[0]), 1e-15f);
            float tc = 2.f * r[co];
            ch[co] = coshf(tc);
            sh[co] = sinhf(tc);
        }
    }
}

// ---------------------------------------------------------------------------
// logmap0 * beta-ratio, transpose -> vt[B,HW,C] bf16, per-pixel sq (fp32).
__global__ void k_logmap(const float* __restrict__ x, unsigned int* __restrict__ vt_u,
                         float* __restrict__ sq, float Rbeta) {
    __shared__ float tile[256][33];
    __shared__ float red[8][32];
    __shared__ float afac[32];
    int tid = threadIdx.x;
    int blk = blockIdx.x;
    int b = blk >> 7;
    int pix0 = (blk & 127) << 5;

    for (int it = 0; it < 8; ++it) {
        int c = it * 32 + (tid >> 3);
        int p4 = (tid & 7) * 4;
        f32x4 v = *(const f32x4*)(x + ((size_t)b * 256 + c) * 4096 + pix0 + p4);
        tile[c][p4] = v[0];
        tile[c][p4 + 1] = v[1];
        tile[c][p4 + 2] = v[2];
        tile[c][p4 + 3] = v[3];
    }
    __syncthreads();

    {
        int part = tid >> 5, p = tid & 31;
        float s = 0.f;
        for (int i = 0; i < 32; ++i) {
            float v = tile[part * 32 + i][p];
            s += v * v;
        }
        red[part][p] = s;
    }
    __syncthreads();
    if (tid < 32) {
        float n2 = 0.f;
        for (int i = 0; i < 8; ++i) n2 += red[i][tid];
        float n = sqrtf(n2);
        float nc = fmaxf(n, 1e-15f);
        float a = atanhf(fminf(nc, 0.9999999f)) / nc * Rbeta;
        afac[tid] = a;
        sq[(size_t)b * 4096 + pix0 + tid] = a * a * n2;
    }
    __syncthreads();

    for (int it = 0; it < 16; ++it) {
        int idx = it * 256 + tid;
        int p = idx >> 7;
        int cp = idx & 127;
        float a = afac[p];
        float v0 = a * tile[2 * cp][p];
        float v1 = a * tile[2 * cp + 1][p];
        union { bf16 h[2]; unsigned int u; } pk;
        pk.h[0] = (bf16)v0;
        pk.h[1] = (bf16)v1;
        vt_u[((size_t)b * 4096 + pix0 + p) * 128 + cp] = pk.u;
    }
}

// ---------------------------------------------------------------------------
// Fused implicit-GEMM conv + hyperbolic FC epilogue — r19 structure with ONE
// change: A-fragment ds_reads are HOISTED above the per-stage vmcnt+barrier
// for taps 1..8 (A buffer is stable within a cc; only tap 0 needs the
// post-barrier read since A was restaged by other waves at the cc boundary).
// Hides ~150-300 cy of LDS latency per stage under the issue/wait window.
__global__ void
__attribute__((amdgpu_flat_work_group_size(512, 512)))
__attribute__((amdgpu_waves_per_eu(4, 4)))
k_hconv(const bf16* __restrict__ vt, const bf16* __restrict__ zt5,
        const float* __restrict__ sq,
        const float* __restrict__ znp, const float* __restrict__ chp,
        const float* __restrict__ shp, float* __restrict__ out) {
    __shared__ __align__(1024) char Asb[16896];      // 16 units x 1056 B
    __shared__ __align__(1024) char Bsb[3][16448];   // 3 bufs x 4 gran x 4112 B
    __shared__ float s_lds[128], lam_lds[128];
    __shared__ float red[128][4];

    int tid = threadIdx.x;
    int bid = blockIdx.x;
    int bh = ((bid & 7) << 6) | (bid >> 3);   // XCD-bijective: 512 = 8 x 64
    int b = bh >> 5, h0 = (bh & 31) << 1;

    // zero halo slots (0 and 65) of the 16 A units, once
    if (tid < 32) {
        int u = tid >> 1, side = tid & 1;
        *(f32x4*)(Asb + u * 1056 + side * 1040) = (f32x4){0.f, 0.f, 0.f, 0.f};
    }

    if (tid >= 128 && tid < 256) {
        int t = tid - 128;
        int h = h0 + (t >> 6), w = t & 63;
        const float* sb = sq + ((size_t)b << 12);
        float q = 0.f;
#pragma unroll
        for (int dh = -1; dh <= 1; ++dh) {
            int hhh = h + dh;
            if ((unsigned)hhh >= 64u) continue;
#pragma unroll
            for (int dw = -1; dw <= 1; ++dw) {
                int ww = w + dw;
                if ((unsigned)ww >= 64u) continue;
                q += sb[hhh * 64 + ww];
            }
        }
        float ncl = fmaxf(sqrtf(q), 1e-15f);
        float p = __expf(2.f * ncl);
        float tt = (p - 1.f) / (p + 1.f);        // tanh(ncl)
        s_lds[t] = tt / ncl;                     // expmap scale
        lam_lds[t] = 2.f / (1.f - tt * tt);
    }

    int wave = tid >> 6, lane = tid & 63;
    int wn = wave & 3, wm = wave >> 2;    // wm row 0..1, wn co-quarter 0..3
    int lrow = lane & 15, lk = lane >> 4;

    f32x4 acc[4][4];
#pragma unroll
    for (int m = 0; m < 4; ++m)
#pragma unroll
        for (int n = 0; n < 4; ++n) acc[m][n] = (f32x4){0.f, 0.f, 0.f, 0.f};

    const bf16* vb = vt + (((size_t)b) << 12) * 256;

    // stage A chunk ccn: 16 units (r4 x g4); 2 loads/wave
    auto stageA = [&](int ccn) {
#pragma unroll
        for (int it = 0; it < 2; ++it) {
            int u = wave * 2 + it;
            int r = u >> 2, g = u & 3;
            int hr = h0 - 1 + r;
            hr = hr < 0 ? 0 : (hr > 63 ? 63 : hr);   // clamped rows never read
            const bf16* gp = vb + ((size_t)(hr * 64 + lane)) * 256 + ccn * 32 + g * 8;
            gload16(gp, Asb + u * 1056 + 16);
        }
    };
    // stage B stage snext into buffer dst: linear 16 KB copy; 2 loads/wave
    auto stageB = [&](char* dst, int snext) {
        const char* src = (const char*)zt5 + (size_t)snext * 16384;
#pragma unroll
        for (int it = 0; it < 2; ++it) {
            int u = wave * 2 + it;
            gload16(src + u * 1024 + lane * 16,
                    dst + (u >> 2) * 4112 + (u & 3) * 1024);
        }
    };

    stageB((char*)Bsb[0], 0);
    stageA(0);
    __syncthreads();                      // drains prologue; s_lds visible
    SBAR();

    // per-lane invariant LDS read bases
    const char* ApB = Asb + lk * 1056 + lrow * 16;
    const int bOff = lk * 4112 + wn * 1024 + lrow * 16;

#pragma unroll 1
    for (int cc = 0; cc < 8; ++cc) {
        const int sbase = cc * 9;
        const bool notlast = (cc < 7);

#pragma unroll
        for (int tap = 0; tap < 9; ++tap) {
            const int s = sbase + tap;
            const int dh = tap / 3 - 1, dw = tap % 3 - 1;
            const char* Ap = ApB + (wm + dh + 1) * 4224 + (dw + 1) * 16;

            bf16x8 a0, a1, a2, a3;
            if (tap != 0) {
                // A buffer stable since barrier(cc,0): read EARLY, latency
                // hides under the B-issue + vmcnt + barrier window.
                a0 = *(const bf16x8*)(Ap);
                a1 = *(const bf16x8*)(Ap + 256);
                a2 = *(const bf16x8*)(Ap + 512);
                a3 = *(const bf16x8*)(Ap + 768);
            }
            if (s < 71) stageB((char*)Bsb[(tap + 1) % 3], s + 1);
            SBAR();
            if (s < 71) { asm volatile("s_waitcnt vmcnt(2)" ::: "memory"); }
            else        { asm volatile("s_waitcnt vmcnt(0)" ::: "memory"); }
            SBAR();
            asm volatile("s_barrier" ::: "memory");   // stage-s data ready
            SBAR();
            if (tap == 0) {
                // A restaged by other waves at the cc boundary: must read
                // after the barrier.
                a0 = *(const bf16x8*)(Ap);
                a1 = *(const bf16x8*)(Ap + 256);
                a2 = *(const bf16x8*)(Ap + 512);
                a3 = *(const bf16x8*)(Ap + 768);
            }

            int hh = h0 + wm + dh;
            if ((unsigned)hh < 64u) {                 // wave-uniform skip
                const char* Bp = (const char*)Bsb[tap % 3] + bOff;
                bf16x8 b0 = *(const bf16x8*)(Bp);
                bf16x8 b1 = *(const bf16x8*)(Bp + 256);
                bf16x8 b2 = *(const bf16x8*)(Bp + 512);
                bf16x8 b3 = *(const bf16x8*)(Bp + 768);
                __builtin_amdgcn_s_setprio(1);
                acc[0][0] = __builtin_amdgcn_mfma_f32_16x16x32_bf16(a0, b0, acc[0][0], 0, 0, 0);
                acc[1][0] = __builtin_amdgcn_mfma_f32_16x16x32_bf16(a1, b0, acc[1][0], 0, 0, 0);
                acc[2][0] = __builtin_amdgcn_mfma_f32_16x16x32_bf16(a2, b0, acc[2][0], 0, 0, 0);
                acc[3][0] = __builtin_amdgcn_mfma_f32_16x16x32_bf16(a3, b0, acc[3][0], 0, 0, 0);
                acc[0][1] = __builtin_amdgcn_mfma_f32_16x16x32_bf16(a0, b1, acc[0][1], 0, 0, 0);
                acc[1][1] = __builtin_amdgcn_mfma_f32_16x16x32_bf16(a1, b1, acc[1][1], 0, 0, 0);
                acc[2][1] = __builtin_amdgcn_mfma_f32_16x16x32_bf16(a2, b1, acc[2][1], 0, 0, 0);
                acc[3][1] = __builtin_amdgcn_mfma_f32_16x16x32_bf16(a3, b1, acc[3][1], 0, 0, 0);
                acc[0][2] = __builtin_amdgcn_mfma_f32_16x16x32_bf16(a0, b2, acc[0][2], 0, 0, 0);
                acc[1][2] = __builtin_amdgcn_mfma_f32_16x16x32_bf16(a1, b2, acc[1][2], 0, 0, 0);
                acc[2][2] = __builtin_amdgcn_mfma_f32_16x16x32_bf16(a2, b2, acc[2][2], 0, 0, 0);
                acc[3][2] = __builtin_amdgcn_mfma_f32_16x16x32_bf16(a3, b2, acc[3][2], 0, 0, 0);
                acc[0][3] = __builtin_amdgcn_mfma_f32_16x16x32_bf16(a0, b3, acc[0][3], 0, 0, 0);
                acc[1][3] = __builtin_amdgcn_mfma_f32_16x16x32_bf16(a1, b3, acc[1][3], 0, 0, 0);
                acc[2][3] = __builtin_amdgcn_mfma_f32_16x16x32_bf16(a2, b3, acc[2][3], 0, 0, 0);
                acc[3][3] = __builtin_amdgcn_mfma_f32_16x16x32_bf16(a3, b3, acc[3][3], 0, 0, 0);
                __builtin_amdgcn_s_setprio(0);
            }
            SBAR();
            if (tap == 8) {
                // cc tail: all A[cc] reads done -> safe to restage A in place
                asm volatile("s_barrier" ::: "memory");
                SBAR();
                if (notlast) stageA(cc + 1);
                SBAR();
            }
        }
    }

    // ---------------- epilogue (fast transcendental forms) ----------------
    float cz[4], sh4[4], tz[4];
#pragma unroll
    for (int n = 0; n < 4; ++n) {
        int co = wn * 64 + n * 16 + lrow;
        float zn = znp[co];
        cz[n] = chp[co] / zn;
        sh4[n] = shp[co];
        tz[n] = 2.f * zn;
    }

#pragma unroll
    for (int m = 0; m < 4; ++m) {
#pragma unroll
        for (int r = 0; r < 4; ++r) {
            int wp = wm * 64 + m * 16 + 4 * lk + r;   // block-local px slot
            float s = s_lds[wp], lam = lam_lds[wp];
            float lm1 = lam - 1.f;
            float psum = 0.f;
#pragma unroll
            for (int n = 0; n < 4; ++n) {
                float xz = s * acc[m][n][r];
                float inner = lam * xz * cz[n] - lm1 * sh4[n];
                float as = __logf(inner + sqrtf(inner * inner + 1.f)); // asinh
                float p = __expf(tz[n] * as);
                float w = 0.5f * (p - __builtin_amdgcn_rcpf(p));       // sinh
                acc[m][n][r] = w;
                psum += w * w;
            }
            psum += __shfl_xor(psum, 1);
            psum += __shfl_xor(psum, 2);
            psum += __shfl_xor(psum, 4);
            psum += __shfl_xor(psum, 8);
            if (lrow == 0) red[wp][wn] = psum;
        }
    }
    __syncthreads();

    float dinv[4][4];
#pragma unroll
    for (int m = 0; m < 4; ++m)
#pragma unroll
        for (int r = 0; r < 4; ++r) {
            int wp = wm * 64 + m * 16 + 4 * lk + r;
            float tot = (red[wp][0] + red[wp][1]) + (red[wp][2] + red[wp][3]);
            dinv[m][r] = __builtin_amdgcn_rcpf(1.f + sqrtf(1.f + tot));
        }

    float* ob = out + (size_t)b * 256 * 4096 + (h0 + wm) * 64;
#pragma unroll
    for (int m = 0; m < 4; ++m) {
#pragma unroll
        for (int n = 0; n < 4; ++n) {
            int co = wn * 64 + n * 16 + lrow;
            f32x4 o;
#pragma unroll
            for (int r = 0; r < 4; ++r) o[r] = acc[m][n][r] * dinv[m][r];
            *(f32x4*)(ob + (size_t)co * 4096 + m * 16 + 4 * lk) = o;
        }
    }
}

// ---------------------------------------------------------------------------
extern "C" void kernel_launch(void* const* d_in, const int* in_sizes, int n_in,
                              void* d_out, int out_size, void* d_ws, size_t ws_size,
                              hipStream_t stream) {
    const float* x = (const float*)d_in[0];   // [16,256,64,64]
    const float* z = (const float*)d_in[1];   // [2304,256]
    const float* r = (const float*)d_in[2];   // [256]
    float* out = (float*)d_out;               // [16,256,64,64]

    char* ws = (char*)d_ws;
    bf16* vt = (bf16*)ws;                         // 33,554,432 B (px-major)
    float* sq = (float*)(ws + 33554432);
    bf16* zt5 = (bf16*)(ws + 34078720);           // 72*16KB = 1,179,648 B
    float* zn = (float*)(ws + 35258368);
    float* ch = (float*)(ws + 35259392);
    float* sh = (float*)(ws + 35260416);
    if (ws_size < 35261440) return;

    double bni = lgamma(128.0) + lgamma(0.5) - lgamma(128.5);
    double bn = lgamma(1152.0) + lgamma(0.5) - lgamma(1152.5);
    float Rbeta = (float)exp(bn - bni);

    k_prep<<<328, 256, 0, stream>>>(z, r, zt5, zn, ch, sh);
    k_logmap<<<2048, 256, 0, stream>>>(x, (unsigned int*)vt, sq, Rbeta);
    k_hconv<<<512, 512, 0, stream>>>(vt, zt5, sq, zn, ch, sh, out);
}

// Round 21
// 118.118 us; speedup vs baseline: 1.0233x; 1.0233x over previous
//
#include <hip/hip_runtime.h>
#include <cmath>

typedef __bf16 bf16;
typedef __bf16 bf16x8 __attribute__((ext_vector_type(8)));
typedef float f32x4 __attribute__((ext_vector_type(4)));

#define SBAR() __builtin_amdgcn_sched_barrier(0)

// B=16, C_IN=256, H=W=64, C_OUT=256, 3x3, stride 1, pad 1, CURV=1

__device__ inline void gload16(const void* g, void* l) {
    __builtin_amdgcn_global_load_lds(
        (const __attribute__((address_space(1))) unsigned int*)g,
        (__attribute__((address_space(3))) unsigned int*)l, 16, 0, 0);
}

// ---------------------------------------------------------------------------
// Fused front kernel.
// Blocks 0..2047: logmap0 * beta-ratio -> vt[B,HW,C] bf16 + per-pixel sq.
// Blocks 2048..2119: weight transform zt5[s][gran4][co256][8ch].
// Blocks 2120..2375: column constants zn/ch/sh (one co per block).
__global__ void k_front(const float* __restrict__ x, const float* __restrict__ z,
                        const float* __restrict__ r, unsigned int* __restrict__ vt_u,
                        float* __restrict__ sq, bf16* __restrict__ zt5,
                        float* __restrict__ zn, float* __restrict__ ch,
                        float* __restrict__ sh, float Rbeta) {
    int blk = blockIdx.x;
    int tid = threadIdx.x;

    if (blk >= 2048) {
        int pb = blk - 2048;
        if (pb < 72) {                    // zt5 build
            int cc = pb / 9, tap = pb % 9;
            int co = tid;
#pragma unroll
            for (int g = 0; g < 4; ++g) {
                bf16x8 pk;
#pragma unroll
                for (int e = 0; e < 8; ++e) {
                    int c = cc * 32 + g * 8 + e;
                    pk[e] = (bf16)z[(size_t)(c * 9 + tap) * 256 + co];
                }
                *(bf16x8*)(zt5 + ((size_t)(pb * 4 + g) * 256 + co) * 8) = pk;
            }
        } else {                          // column constants
            __shared__ float redp[256];
            int co = pb - 72, t = tid;
            float s = 0.f;
            for (int i = 0; i < 9; ++i) {
                float v = z[(size_t)(i * 256 + t) * 256 + co];
                s += v * v;
            }
            redp[t] = s;
            __syncthreads();
            for (int off = 128; off >= 1; off >>= 1) {
                if (t < off) redp[t] += redp[t + off];
                __syncthreads();
            }
            if (t == 0) {
                zn[co] = fmaxf(sqrtf(redp[0]), 1e-15f);
                float tc = 2.f * r[co];
                ch[co] = coshf(tc);
                sh[co] = sinhf(tc);
            }
        }
        return;
    }

    __shared__ float tile[256][33];
    __shared__ float red[8][32];
    __shared__ float afac[32];
    int b = blk >> 7;
    int pix0 = (blk & 127) << 5;

    for (int it = 0; it < 8; ++it) {
        int c = it * 32 + (tid >> 3);
        int p4 = (tid & 7) * 4;
        f32x4 v = *(const f32x4*)(x + ((size_t)b * 256 + c) * 4096 + pix0 + p4);
        tile[c][p4] = v[0];
        tile[c][p4 + 1] = v[1];
        tile[c][p4 + 2] = v[2];
        tile[c][p4 + 3] = v[3];
    }
    __syncthreads();

    {
        int part = tid >> 5, p = tid & 31;
        float s = 0.f;
        for (int i = 0; i < 32; ++i) {
            float v = tile[part * 32 + i][p];
            s += v * v;
        }
        red[part][p] = s;
    }
    __syncthreads();
    if (tid < 32) {
        float n2 = 0.f;
        for (int i = 0; i < 8; ++i) n2 += red[i][tid];
        float n = sqrtf(n2);
        float nc = fmaxf(n, 1e-15f);
        float a = atanhf(fminf(nc, 0.9999999f)) / nc * Rbeta;
        afac[tid] = a;
        sq[(size_t)b * 4096 + pix0 + tid] = a * a * n2;
    }
    __syncthreads();

    for (int it = 0; it < 16; ++it) {
        int idx = it * 256 + tid;
        int p = idx >> 7;
        int cp = idx & 127;
        float a = afac[p];
        float v0 = a * tile[2 * cp][p];
        float v1 = a * tile[2 * cp + 1][p];
        union { bf16 h[2]; unsigned int u; } pk;
        pk.h[0] = (bf16)v0;
        pk.h[1] = (bf16)v1;
        vt_u[((size_t)b * 4096 + pix0 + p) * 128 + cp] = pk.u;
    }
}

// ---------------------------------------------------------------------------
// Fused implicit-GEMM conv + hyperbolic FC epilogue — r20 verbatim (best
// measured hconv: 98.2 us). Block: 2 rows x 256 co, 8 waves; wave 64px x
// 64co (acc[4][4]); A single-buffered halo layout (restage at tap8 behind
// release barrier), B triple-buffered (static tap%3 parity); counted
// vmcnt(2), vmcnt(0) at s=71; A-frag reads hoisted pre-barrier for taps 1-8;
// fused 3x3 box-sum of sq; fast-transcendental epilogue.
__global__ void
__attribute__((amdgpu_flat_work_group_size(512, 512)))
__attribute__((amdgpu_waves_per_eu(4, 4)))
k_hconv(const bf16* __restrict__ vt, const bf16* __restrict__ zt5,
        const float* __restrict__ sq,
        const float* __restrict__ znp, const float* __restrict__ chp,
        const float* __restrict__ shp, float* __restrict__ out) {
    __shared__ __align__(1024) char Asb[16896];      // 16 units x 1056 B
    __shared__ __align__(1024) char Bsb[3][16448];   // 3 bufs x 4 gran x 4112 B
    __shared__ float s_lds[128], lam_lds[128];
    __shared__ float red[128][4];

    int tid = threadIdx.x;
    int bid = blockIdx.x;
    int bh = ((bid & 7) << 6) | (bid >> 3);   // XCD-bijective: 512 = 8 x 64
    int b = bh >> 5, h0 = (bh & 31) << 1;

    // zero halo slots (0 and 65) of the 16 A units, once
    if (tid < 32) {
        int u = tid >> 1, side = tid & 1;
        *(f32x4*)(Asb + u * 1056 + side * 1040) = (f32x4){0.f, 0.f, 0.f, 0.f};
    }

    if (tid >= 128 && tid < 256) {
        int t = tid - 128;
        int h = h0 + (t >> 6), w = t & 63;
        const float* sb = sq + ((size_t)b << 12);
        float q = 0.f;
#pragma unroll
        for (int dh = -1; dh <= 1; ++dh) {
            int hhh = h + dh;
            if ((unsigned)hhh >= 64u) continue;
#pragma unroll
            for (int dw = -1; dw <= 1; ++dw) {
                int ww = w + dw;
                if ((unsigned)ww >= 64u) continue;
                q += sb[hhh * 64 + ww];
            }
        }
        float ncl = fmaxf(sqrtf(q), 1e-15f);
        float p = __expf(2.f * ncl);
        float tt = (p - 1.f) / (p + 1.f);        // tanh(ncl)
        s_lds[t] = tt / ncl;                     // expmap scale
        lam_lds[t] = 2.f / (1.f - tt * tt);
    }

    int wave = tid >> 6, lane = tid & 63;
    int wn = wave & 3, wm = wave >> 2;    // wm row 0..1, wn co-quarter 0..3
    int lrow = lane & 15, lk = lane >> 4;

    f32x4 acc[4][4];
#pragma unroll
    for (int m = 0; m < 4; ++m)
#pragma unroll
        for (int n = 0; n < 4; ++n) acc[m][n] = (f32x4){0.f, 0.f, 0.f, 0.f};

    const bf16* vb = vt + (((size_t)b) << 12) * 256;

    // stage A chunk ccn: 16 units (r4 x g4); 2 loads/wave
    auto stageA = [&](int ccn) {
#pragma unroll
        for (int it = 0; it < 2; ++it) {
            int u = wave * 2 + it;
            int r = u >> 2, g = u & 3;
            int hr = h0 - 1 + r;
            hr = hr < 0 ? 0 : (hr > 63 ? 63 : hr);   // clamped rows never read
            const bf16* gp = vb + ((size_t)(hr * 64 + lane)) * 256 + ccn * 32 + g * 8;
            gload16(gp, Asb + u * 1056 + 16);
        }
    };
    // stage B stage snext into buffer dst: linear 16 KB copy; 2 loads/wave
    auto stageB = [&](char* dst, int snext) {
        const char* src = (const char*)zt5 + (size_t)snext * 16384;
#pragma unroll
        for (int it = 0; it < 2; ++it) {
            int u = wave * 2 + it;
            gload16(src + u * 1024 + lane * 16,
                    dst + (u >> 2) * 4112 + (u & 3) * 1024);
        }
    };

    stageB((char*)Bsb[0], 0);
    stageA(0);
    __syncthreads();                      // drains prologue; s_lds visible
    SBAR();

    // per-lane invariant LDS read bases
    const char* ApB = Asb + lk * 1056 + lrow * 16;
    const int bOff = lk * 4112 + wn * 1024 + lrow * 16;

#pragma unroll 1
    for (int cc = 0; cc < 8; ++cc) {
        const int sbase = cc * 9;
        const bool notlast = (cc < 7);

#pragma unroll
        for (int tap = 0; tap < 9; ++tap) {
            const int s = sbase + tap;
            const int dh = tap / 3 - 1, dw = tap % 3 - 1;
            const char* Ap = ApB + (wm + dh + 1) * 4224 + (dw + 1) * 16;

            bf16x8 a0, a1, a2, a3;
            if (tap != 0) {
                // A buffer stable since barrier(cc,0): read EARLY, latency
                // hides under the B-issue + vmcnt + barrier window.
                a0 = *(const bf16x8*)(Ap);
                a1 = *(const bf16x8*)(Ap + 256);
                a2 = *(const bf16x8*)(Ap + 512);
                a3 = *(const bf16x8*)(Ap + 768);
            }
            if (s < 71) stageB((char*)Bsb[(tap + 1) % 3], s + 1);
            SBAR();
            if (s < 71) { asm volatile("s_waitcnt vmcnt(2)" ::: "memory"); }
            else        { asm volatile("s_waitcnt vmcnt(0)" ::: "memory"); }
            SBAR();
            asm volatile("s_barrier" ::: "memory");   // stage-s data ready
            SBAR();
            if (tap == 0) {
                a0 = *(const bf16x8*)(Ap);
                a1 = *(const bf16x8*)(Ap + 256);
                a2 = *(const bf16x8*)(Ap + 512);
                a3 = *(const bf16x8*)(Ap + 768);
            }

            int hh = h0 + wm + dh;
            if ((unsigned)hh < 64u) {                 // wave-uniform skip
                const char* Bp = (const char*)Bsb[tap % 3] + bOff;
                bf16x8 b0 = *(const bf16x8*)(Bp);
                bf16x8 b1 = *(const bf16x8*)(Bp + 256);
                bf16x8 b2 = *(const bf16x8*)(Bp + 512);
                bf16x8 b3 = *(const bf16x8*)(Bp + 768);
                __builtin_amdgcn_s_setprio(1);
                acc[0][0] = __builtin_amdgcn_mfma_f32_16x16x32_bf16(a0, b0, acc[0][0], 0, 0, 0);
                acc[1][0] = __builtin_amdgcn_mfma_f32_16x16x32_bf16(a1, b0, acc[1][0], 0, 0, 0);
                acc[2][0] = __builtin_amdgcn_mfma_f32_16x16x32_bf16(a2, b0, acc[2][0], 0, 0, 0);
                acc[3][0] = __builtin_amdgcn_mfma_f32_16x16x32_bf16(a3, b0, acc[3][0], 0, 0, 0);
                acc[0][1] = __builtin_amdgcn_mfma_f32_16x16x32_bf16(a0, b1, acc[0][1], 0, 0, 0);
                acc[1][1] = __builtin_amdgcn_mfma_f32_16x16x32_bf16(a1, b1, acc[1][1], 0, 0, 0);
                acc[2][1] = __builtin_amdgcn_mfma_f32_16x16x32_bf16(a2, b1, acc[2][1], 0, 0, 0);
                acc[3][1] = __builtin_amdgcn_mfma_f32_16x16x32_bf16(a3, b1, acc[3][1], 0, 0, 0);
                acc[0][2] = __builtin_amdgcn_mfma_f32_16x16x32_bf16(a0, b2, acc[0][2], 0, 0, 0);
                acc[1][2] = __builtin_amdgcn_mfma_f32_16x16x32_bf16(a1, b2, acc[1][2], 0, 0, 0);
                acc[2][2] = __builtin_amdgcn_mfma_f32_16x16x32_bf16(a2, b2, acc[2][2], 0, 0, 0);
                acc[3][2] = __builtin_amdgcn_mfma_f32_16x16x32_bf16(a3, b2, acc[3][2], 0, 0, 0);
                acc[0][3] = __builtin_amdgcn_mfma_f32_16x16x32_bf16(a0, b3, acc[0][3], 0, 0, 0);
                acc[1][3] = __builtin_amdgcn_mfma_f32_16x16x32_bf16(a1, b3, acc[1][3], 0, 0, 0);
                acc[2][3] = __builtin_amdgcn_mfma_f32_16x16x32_bf16(a2, b3, acc[2][3], 0, 0, 0);
                acc[3][3] = __builtin_amdgcn_mfma_f32_16x16x32_bf16(a3, b3, acc[3][3], 0, 0, 0);
                __builtin_amdgcn_s_setprio(0);
            }
            SBAR();
            if (tap == 8) {
                // cc tail: all A[cc] reads done -> safe to restage A in place
                asm volatile("s_barrier" ::: "memory");
                SBAR();
                if (notlast) stageA(cc + 1);
                SBAR();
            }
        }
    }

    // ---------------- epilogue (fast transcendental forms) ----------------
    float cz[4], sh4[4], tz[4];
#pragma unroll
    for (int n = 0; n < 4; ++n) {
        int co = wn * 64 + n * 16 + lrow;
        float zn = znp[co];
        cz[n] = chp[co] / zn;
        sh4[n] = shp[co];
        tz[n] = 2.f * zn;
    }

#pragma unroll
    for (int m = 0; m < 4; ++m) {
#pragma unroll
        for (int r = 0; r < 4; ++r) {
            int wp = wm * 64 + m * 16 + 4 * lk + r;   // block-local px slot
            float s = s_lds[wp], lam = lam_lds[wp];
            float lm1 = lam - 1.f;
            float psum = 0.f;
#pragma unroll
            for (int n = 0; n < 4; ++n) {
                float xz = s * acc[m][n][r];
                float inner = lam * xz * cz[n] - lm1 * sh4[n];
                float as = __logf(inner + sqrtf(inner * inner + 1.f)); // asinh
                float p = __expf(tz[n] * as);
                float w = 0.5f * (p - __builtin_amdgcn_rcpf(p));       // sinh
                acc[m][n][r] = w;
                psum += w * w;
            }
            psum += __shfl_xor(psum, 1);
            psum += __shfl_xor(psum, 2);
            psum += __shfl_xor(psum, 4);
            psum += __shfl_xor(psum, 8);
            if (lrow == 0) red[wp][wn] = psum;
        }
    }
    __syncthreads();

    float dinv[4][4];
#pragma unroll
    for (int m = 0; m < 4; ++m)
#pragma unroll
        for (int r = 0; r < 4; ++r) {
            int wp = wm * 64 + m * 16 + 4 * lk + r;
            float tot = (red[wp][0] + red[wp][1]) + (red[wp][2] + red[wp][3]);
            dinv[m][r] = __builtin_amdgcn_rcpf(1.f + sqrtf(1.f + tot));
        }

    float* ob = out + (size_t)b * 256 * 4096 + (h0 + wm) * 64;
#pragma unroll
    for (int m = 0; m < 4; ++m) {
#pragma unroll
        for (int n = 0; n < 4; ++n) {
            int co = wn * 64 + n * 16 + lrow;
            f32x4 o;
#pragma unroll
            for (int r = 0; r < 4; ++r) o[r] = acc[m][n][r] * dinv[m][r];
            *(f32x4*)(ob + (size_t)co * 4096 + m * 16 + 4 * lk) = o;
        }
    }
}

// ---------------------------------------------------------------------------
extern "C" void kernel_launch(void* const* d_in, const int* in_sizes, int n_in,
                              void* d_out, int out_size, void* d_ws, size_t ws_size,
                              hipStream_t stream) {
    const float* x = (const float*)d_in[0];   // [16,256,64,64]
    const float* z = (const float*)d_in[1];   // [2304,256]
    const float* r = (const float*)d_in[2];   // [256]
    float* out = (float*)d_out;               // [16,256,64,64]

    char* ws = (char*)d_ws;
    bf16* vt = (bf16*)ws;                         // 33,554,432 B (px-major)
    float* sq = (float*)(ws + 33554432);
    bf16* zt5 = (bf16*)(ws + 34078720);           // 72*16KB = 1,179,648 B
    float* zn = (float*)(ws + 35258368);
    float* ch = (float*)(ws + 35259392);
    float* sh = (float*)(ws + 35260416);
    if (ws_size < 35261440) return;

    double bni = lgamma(128.0) + lgamma(0.5) - lgamma(128.5);
    double bn = lgamma(1152.0) + lgamma(0.5) - lgamma(1152.5);
    float Rbeta = (float)exp(bn - bni);

    k_front<<<2376, 256, 0, stream>>>(x, z, r, (unsigned int*)vt, sq, zt5,
                                      zn, ch, sh, Rbeta);
    k_hconv<<<512, 512, 0, stream>>>(vt, zt5, sq, zn, ch, sh, out);
}